// Round 16
// baseline (96.474 us; speedup 1.0000x reference)
//
#include <hip/hip_runtime.h>
#include <hip/hip_fp16.h>
#include <math.h>

#define IMG    512
#define TWD    64        // tile width
#define NSTRIP 4         // 32-row strips per block
#define BROWS  128       // output rows per block
#define WIN    42        // rolling hb window rows
#define HS2    34        // hb row stride in __half2 (136 B)
#define NBLK   1536      // 8 * 4 * 48
#define NPIX   12582912.0

// Normalized 11-tap Gaussian, sigma=1.5 — inline literals
constexpr float G[11] = {
    0.00102838f, 0.00759876f, 0.03600077f, 0.10936069f, 0.21300554f,
    0.26601173f,
    0.21300554f, 0.10936069f, 0.03600077f, 0.00759876f, 0.00102838f};

// loads: 6 float4 pairs. MASKED -> clamped addresses (mask applied in conv).
template<bool MASKED>
__device__ __forceinline__ void issue_loads(
    const float* __restrict__ xb, const float* __restrict__ yb,
    int grow, int gc0, float4 (&fx)[6], float4 (&fy)[6])
{
    if (MASKED) {
        const float* __restrict__ px = xb + min(max(grow, 0), IMG - 1) * IMG;
        const float* __restrict__ py = yb + min(max(grow, 0), IMG - 1) * IMG;
#pragma unroll
        for (int i = 0; i < 6; ++i) {
            int gcl = min(max(gc0 + 4 * i, 0), IMG - 4);
            fx[i] = *(const float4*)(px + gcl);
            fy[i] = *(const float4*)(py + gcl);
        }
    } else {
        const float* __restrict__ px = xb + grow * IMG + gc0;
        const float* __restrict__ py = yb + grow * IMG + gc0;
#pragma unroll
        for (int i = 0; i < 6; ++i) {
            fx[i] = *(const float4*)(px + 4 * i);
            fy[i] = *(const float4*)(py + 4 * i);
        }
    }
}

// h-conv of one row x 8 outputs; fp32 math, half2 store. MASKED folds away.
template<bool MASKED>
__device__ __forceinline__ void conv_store(
    __half2 (&hb2)[4][WIN][HS2],
    const float4 (&fx)[6], const float4 (&fy)[6],
    int grow, int gc0, int bufrow, int hg)
{
    float gm[6];
#pragma unroll
    for (int i = 0; i < 6; ++i) {
        if (MASKED) {
            const float rm = ((unsigned)grow < IMG) ? 1.f : 0.f;
            gm[i] = ((unsigned)(gc0 + 4 * i) < IMG) ? rm : 0.f;
        } else gm[i] = 1.f;
    }
    float ax[8] = {}, ay[8] = {}, ass[8] = {}, axy[8] = {};
#pragma unroll
    for (int i = 0; i < 6; ++i) {
        const float vx4[4] = {fx[i].x, fx[i].y, fx[i].z, fx[i].w};
        const float vy4[4] = {fy[i].x, fy[i].y, fy[i].z, fy[i].w};
#pragma unroll
        for (int c = 0; c < 4; ++c) {
            const int j = 4 * i + c;          // raw col idx 0..23
            if (j < 3 || j > 20) continue;    // compile-time pruned
            const float a  = MASKED ? vx4[c] * gm[i] : vx4[c];
            const float b  = MASKED ? vy4[c] * gm[i] : vy4[c];
            const float ss = fmaf(a, a, b * b);
            const float xy = a * b;
#pragma unroll
            for (int e = 0; e < 8; ++e) {
                const int k = j - 3 - e;      // tap index, compile-time
                if (k >= 0 && k <= 10) {
                    ax[e]  = fmaf(G[k], a,  ax[e]);
                    ay[e]  = fmaf(G[k], b,  ay[e]);
                    ass[e] = fmaf(G[k], ss, ass[e]);
                    axy[e] = fmaf(G[k], xy, axy[e]);
                }
            }
        }
    }
    const int p0 = 4 * hg;
#pragma unroll
    for (int p = 0; p < 4; ++p) {
        hb2[0][bufrow][p0 + p] = __floats2half2_rn(ax[2*p],  ax[2*p+1]);
        hb2[1][bufrow][p0 + p] = __floats2half2_rn(ay[2*p],  ay[2*p+1]);
        hb2[2][bufrow][p0 + p] = __floats2half2_rn(ass[2*p], ass[2*p+1]);
        hb2[3][bufrow][p0 + p] = __floats2half2_rn(axy[2*p], axy[2*p+1]);
    }
}

// strip-0 fill task (load + conv fused)
template<bool MASKED>
__device__ __forceinline__ void fill_task(
    __half2 (&hb2)[4][WIN][HS2],
    const float* __restrict__ xb, const float* __restrict__ yb,
    int rbase0, int c0, int t)
{
    const int brow = t >> 3, g = t & 7;
    const int grow = rbase0 - 5 + brow;
    const int gc0  = c0 - 8 + 8 * g;
    float4 fx[6], fy[6];
    issue_loads<MASKED>(xb, yb, grow, gc0, fx, fy);
    conv_store<MASKED>(hb2, fx, fy, grow, gc0, brow, g);
}

// v-pass: 2 cols x 4 rows, packed __hfma2 conv, SSIM in fp32
__device__ __forceinline__ float vpass16(
    const __half2 (&hb2)[4][WIN][HS2], const __half2 (&Gh)[11],
    int rb, int cg)
{
    __half2 vr[4][4];
    const __half2 z2 = __floats2half2_rn(0.f, 0.f);
#pragma unroll
    for (int q = 0; q < 4; ++q)
#pragma unroll
        for (int j = 0; j < 4; ++j) vr[q][j] = z2;
#pragma unroll
    for (int q = 0; q < 4; ++q)
#pragma unroll
        for (int k = 0; k < 14; ++k) {
            __half2 v = hb2[q][rb + k][cg];
#pragma unroll
            for (int j = 0; j < 4; ++j)
                if (k - j >= 0 && k - j <= 10)
                    vr[q][j] = __hfma2(Gh[k - j], v, vr[q][j]);
        }
    float s = 0.f;
#pragma unroll
    for (int j = 0; j < 4; ++j) {
        float2 mxv  = __half22float2(vr[0][j]);
        float2 myv  = __half22float2(vr[1][j]);
        float2 mssv = __half22float2(vr[2][j]);
        float2 mxyv = __half22float2(vr[3][j]);
        const float mxa[2]  = {mxv.x, mxv.y};
        const float mya[2]  = {myv.x, myv.y};
        const float mssa[2] = {mssv.x, mssv.y};
        const float mxya[2] = {mxyv.x, mxyv.y};
#pragma unroll
        for (int e = 0; e < 2; ++e) {
            float mx = mxa[e], my = mya[e];
            float mss = mssa[e], mxy = mxya[e];
            float mx2 = mx * mx, my2 = my * my, mxmy = mx * my;
            float num = (2.f * mxmy + 0.0001f) * (2.f * (mxy - mxmy) + 0.0009f);
            float den = (mx2 + my2 + 0.0001f) * ((mss - mx2 - my2) + 0.0009f);
            s += num * __builtin_amdgcn_rcpf(den);
        }
    }
    return s;
}

// 4-strip rolling window, fp16 hb, per-strip interior specialization,
// T14 register prefetch, XCD chunk swizzle.
// NOTE: plain __launch_bounds__(256) — a min-wave hint caps VGPRs (84) and
// forces scratch traffic (R8-R12: 20-166 MB WRITE_SIZE).
__global__ __launch_bounds__(256) void ssim_tile_kernel(
    const float* __restrict__ x, const float* __restrict__ y,
    float* __restrict__ partial)
{
    __shared__ __half2 hb2[4][WIN][HS2];   // 22.3 KB
    __shared__ float wsum[4];

    const int tid = threadIdx.x;
    const int bid = blockIdx.x;
    const int nb  = (bid & 7) * (NBLK / 8) + (bid >> 3);  // XCD chunk swizzle
    const int z   = nb >> 5;               // image plane 0..47 (32 blocks each)
    const int rem = nb & 31;
    const int by  = rem >> 3, bx = rem & 7;
    const int c0 = bx * TWD;
    const int rbase0 = by * BROWS;
    const size_t ioff = (size_t)z * IMG * IMG;
    const float* __restrict__ xb = x + ioff;
    const float* __restrict__ yb = y + ioff;

    const bool xmask = (bx == 0) | (bx == 7);

    __half2 Gh[11];
#pragma unroll
    for (int k = 0; k < 11; ++k) Gh[k] = __floats2half2_rn(G[k], G[k]);

    const int hrow = tid >> 3;          // strip h-task row 0..31
    const int hg   = tid & 7;
    const int gc0  = c0 - 8 + 8 * hg;
    const int cg   = tid & 31;          // v-pass half2 col
    const int rb   = (tid >> 5) * 4;    // v-pass rows rb..rb+3
    float lsum = 0.f;

    float4 pfx[6], pfy[6];              // next-strip prefetch registers

    // ---- strip 0 fill: 42 rows x 8 groups = 336 tasks ----
    if (xmask | (by == 0)) {
        fill_task<true>(hb2, xb, yb, rbase0, c0, tid);
        if (tid < 80) fill_task<true>(hb2, xb, yb, rbase0, c0, tid + 256);
    } else {
        fill_task<false>(hb2, xb, yb, rbase0, c0, tid);
        if (tid < 80) fill_task<false>(hb2, xb, yb, rbase0, c0, tid + 256);
    }
    // prefetch strip 1 rows (rbase0+37..68, always y-interior at by<=3)
    if (xmask) issue_loads<true >(xb, yb, rbase0 + 37 + hrow, gc0, pfx, pfy);
    else       issue_loads<false>(xb, yb, rbase0 + 37 + hrow, gc0, pfx, pfy);
    __syncthreads();
    lsum += vpass16(hb2, Gh, rb, cg);
    __syncthreads();

#pragma unroll
    for (int s = 1; s < NSTRIP; ++s) {
        const int sbase = rbase0 + 32 * s;
        // carry rows 32..41 -> 0..9 : 640 float2 moves (32 data half2/row)
#pragma unroll
        for (int k = 0; k < 3; ++k) {
            int idx = tid + k * 256;
            if (idx < 640) {
                int q = idx / 160, rr = (idx - q * 160) >> 4, p = idx & 15;
                *(float2*)&hb2[q][rr][2 * p] =
                    *(const float2*)&hb2[q][32 + rr][2 * p];
            }
        }
        __syncthreads();
        // h-conv from prefetched regs -> window rows 10..41
        const bool smask = xmask | ((by == 3) & (s == 3));
        if (smask) conv_store<true >(hb2, pfx, pfy, sbase + 5 + hrow, gc0, 10 + hrow, hg);
        else       conv_store<false>(hb2, pfx, pfy, sbase + 5 + hrow, gc0, 10 + hrow, hg);
        // issue next strip's loads (hidden under v-pass + next carry)
        if (s < NSTRIP - 1) {
            const int ngrow = rbase0 + 32 * (s + 1) + 5 + hrow;
            const bool nmask = xmask | ((by == 3) & (s + 1 == 3));
            if (nmask) issue_loads<true >(xb, yb, ngrow, gc0, pfx, pfy);
            else       issue_loads<false>(xb, yb, ngrow, gc0, pfx, pfy);
        }
        __syncthreads();
        lsum += vpass16(hb2, Gh, rb, cg);
        __syncthreads();
    }

    // ---- block reduction -> plain store ----
#pragma unroll
    for (int off = 32; off > 0; off >>= 1)
        lsum += __shfl_down(lsum, off, 64);
    if ((tid & 63) == 0) wsum[tid >> 6] = lsum;
    __syncthreads();
    if (tid == 0)
        partial[bid] = wsum[0] + wsum[1] + wsum[2] + wsum[3];
}

__global__ __launch_bounds__(1024) void ssim_reduce_kernel(
    const float* __restrict__ partial, float* __restrict__ out)
{
    __shared__ double ws[16];
    const int tid = threadIdx.x;
    double s = 0.0;
    for (int i = tid; i < NBLK; i += 1024) s += (double)partial[i];
#pragma unroll
    for (int off = 32; off > 0; off >>= 1)
        s += __shfl_down(s, off, 64);
    if ((tid & 63) == 0) ws[tid >> 6] = s;
    __syncthreads();
    if (tid == 0) {
        double t = 0.0;
#pragma unroll
        for (int w = 0; w < 16; ++w) t += ws[w];
        double mean = t / NPIX;
        out[0] = (float)(-log10(mean));  // loss
        out[1] = (float)mean;            // ssim_mean
    }
}

extern "C" void kernel_launch(void* const* d_in, const int* in_sizes, int n_in,
                              void* d_out, int out_size, void* d_ws, size_t ws_size,
                              hipStream_t stream)
{
    const float* x = (const float*)d_in[0];
    const float* y = (const float*)d_in[1];
    float* out     = (float*)d_out;
    float* partial = (float*)d_ws;      // 1536 floats, fully rewritten each call

    ssim_tile_kernel<<<NBLK, 256, 0, stream>>>(x, y, partial);
    ssim_reduce_kernel<<<1, 1024, 0, stream>>>(partial, out);
}

// Round 17
// 50.813 us; speedup vs baseline: 1.8986x; 1.8986x over previous
//
#include <hip/hip_runtime.h>
#include <hip/hip_fp16.h>
#include <math.h>

#define IMG    512
#define TWD    64        // tile width
#define NSTRIP 2         // 32-row strips per block
#define BROWS  64        // output rows per block
#define WIN    42        // rolling hb window rows
#define HS2    34        // hb row stride in __half2 units (136 B)
#define NBLK   3072      // 8 * 8 * 48
#define NPIX   12582912.0

// Normalized 11-tap Gaussian, sigma=1.5 — inline literals
constexpr float G[11] = {
    0.00102838f, 0.00759876f, 0.03600077f, 0.10936069f, 0.21300554f,
    0.26601173f,
    0.21300554f, 0.10936069f, 0.03600077f, 0.00759876f, 0.00102838f};

// Clamped raw loads of 6 float4 per array (group all-valid or all-invalid,
// masked at consume time). Straight-line, no CFG.
__device__ __forceinline__ void issue_loads(
    const float* __restrict__ px, const float* __restrict__ py, int gc0,
    float4 (&fx)[6], float4 (&fy)[6])
{
#pragma unroll
    for (int i = 0; i < 6; ++i) {
        int gcl = min(max(gc0 + 4 * i, 0), IMG - 4);
        fx[i] = *(const float4*)(px + gcl);
        fy[i] = *(const float4*)(py + gcl);
    }
}

// h-conv (fp32) of one row x 8 outputs, packed to half2 and stored to LDS.
__device__ __forceinline__ void conv_store(
    __half2 (&hb2)[4][WIN][HS2],
    const float4 (&fx)[6], const float4 (&fy)[6],
    int grow, int gc0, int bufrow, int hg)
{
    const float rm = ((unsigned)grow < IMG) ? 1.f : 0.f;
    float ax[8] = {}, ay[8] = {}, ass[8] = {}, axy[8] = {};
#pragma unroll
    for (int i = 0; i < 6; ++i) {
        const float gm = ((unsigned)(gc0 + 4 * i) < IMG) ? rm : 0.f;
        const float vx4[4] = {fx[i].x, fx[i].y, fx[i].z, fx[i].w};
        const float vy4[4] = {fy[i].x, fy[i].y, fy[i].z, fy[i].w};
#pragma unroll
        for (int c = 0; c < 4; ++c) {
            const int j = 4 * i + c;          // raw col idx 0..23
            if (j < 3 || j > 20) continue;    // compile-time pruned
            const float a  = vx4[c] * gm;
            const float b  = vy4[c] * gm;
            const float ss = fmaf(a, a, b * b);
            const float xy = a * b;
#pragma unroll
            for (int e = 0; e < 8; ++e) {
                const int k = j - 3 - e;      // tap index, compile-time
                if (k >= 0 && k <= 10) {
                    ax[e]  = fmaf(G[k], a,  ax[e]);
                    ay[e]  = fmaf(G[k], b,  ay[e]);
                    ass[e] = fmaf(G[k], ss, ass[e]);
                    axy[e] = fmaf(G[k], xy, axy[e]);
                }
            }
        }
    }
    const int p0 = 4 * hg;                    // first half2 col of this task
#pragma unroll
    for (int p = 0; p < 4; ++p) {
        hb2[0][bufrow][p0 + p] = __floats2half2_rn(ax[2*p],  ax[2*p+1]);
        hb2[1][bufrow][p0 + p] = __floats2half2_rn(ay[2*p],  ay[2*p+1]);
        hb2[2][bufrow][p0 + p] = __floats2half2_rn(ass[2*p], ass[2*p+1]);
        hb2[3][bufrow][p0 + p] = __floats2half2_rn(axy[2*p], axy[2*p+1]);
    }
}

// v-pass: 2 cols (one half2) x 4 rows, packed __hfma2 conv, SSIM in fp32.
__device__ __forceinline__ float vpass16(
    const __half2 (&hb2)[4][WIN][HS2], const __half2 (&Gh)[11],
    int rb, int cg)
{
    __half2 vr[4][4];
    const __half2 z2 = __floats2half2_rn(0.f, 0.f);
#pragma unroll
    for (int q = 0; q < 4; ++q)
#pragma unroll
        for (int j = 0; j < 4; ++j) vr[q][j] = z2;
#pragma unroll
    for (int q = 0; q < 4; ++q)
#pragma unroll
        for (int k = 0; k < 14; ++k) {
            __half2 v = hb2[q][rb + k][cg];
#pragma unroll
            for (int j = 0; j < 4; ++j)
                if (k - j >= 0 && k - j <= 10)
                    vr[q][j] = __hfma2(Gh[k - j], v, vr[q][j]);
        }
    float s = 0.f;
#pragma unroll
    for (int j = 0; j < 4; ++j) {
        float2 mxv  = __half22float2(vr[0][j]);
        float2 myv  = __half22float2(vr[1][j]);
        float2 mssv = __half22float2(vr[2][j]);
        float2 mxyv = __half22float2(vr[3][j]);
        const float mxa[2]  = {mxv.x, mxv.y};
        const float mya[2]  = {myv.x, myv.y};
        const float mssa[2] = {mssv.x, mssv.y};
        const float mxya[2] = {mxyv.x, mxyv.y};
#pragma unroll
        for (int e = 0; e < 2; ++e) {
            float mx = mxa[e], my = mya[e];
            float mss = mssa[e], mxy = mxya[e];
            float mx2 = mx * mx, my2 = my * my, mxmy = mx * my;
            float num = (2.f * mxmy + 0.0001f) * (2.f * (mxy - mxmy) + 0.0009f);
            float den = (mx2 + my2 + 0.0001f) * ((mss - mx2 - my2) + 0.0009f);
            s += num * __builtin_amdgcn_rcpf(den);
        }
    }
    return s;
}

// R14 structure exactly (2-strip rolling fp16 window, T14 prefetch, single
// masked code path) + XCD chunk swizzle (R15-proven: FETCH halves).
// 3072 % 8 == 0 -> bijective; each XCD owns 6 whole images.
__global__ __launch_bounds__(256) void ssim_tile_kernel(
    const float* __restrict__ x, const float* __restrict__ y,
    float* __restrict__ partial)
{
    __shared__ __half2 hb2[4][WIN][HS2];   // 22.3 KB
    __shared__ float wsum[4];

    const int tid = threadIdx.x;
    const int bid = blockIdx.x;
    const int nb  = (bid & 7) * (NBLK / 8) + (bid >> 3);  // XCD chunk swizzle
    const int z   = nb >> 6;               // image 0..47 (64 blocks/image)
    const int rem = nb & 63;
    const int by  = rem >> 3, bx = rem & 7;
    const int c0 = bx * TWD;
    const int rbase0 = by * BROWS;
    const size_t ioff = (size_t)z * IMG * IMG;
    const float* __restrict__ xb = x + ioff;
    const float* __restrict__ yb = y + ioff;

    __half2 Gh[11];
#pragma unroll
    for (int k = 0; k < 11; ++k) Gh[k] = __floats2half2_rn(G[k], G[k]);

    const int hrow = tid >> 3;          // h-task row 0..31 (s>=1)
    const int hg   = tid & 7;           // 8-output col group
    const int gc0  = c0 - 8 + 8 * hg;   // first of 24 raw cols
    const int cg   = tid & 31;          // v-pass half2 col (cols 2cg,2cg+1)
    const int rb   = (tid >> 5) * 4;    // v-pass rows rb..rb+3
    float lsum = 0.f;

    float4 pfx[6], pfy[6];              // next-strip prefetch registers

    // ---- strip 0: fill all 42 window rows (336 tasks, 2 rounds) ----
    {
        int brow = tid >> 3, g = tid & 7;
        int grow = rbase0 - 5 + brow;
        int tg0 = c0 - 8 + 8 * g;
        const float* px = xb + min(max(grow, 0), IMG - 1) * IMG;
        const float* py = yb + min(max(grow, 0), IMG - 1) * IMG;
        float4 fx[6], fy[6];
        issue_loads(px, py, tg0, fx, fy);
        conv_store(hb2, fx, fy, grow, tg0, brow, g);
    }
    if (tid < 80) {
        int t = tid + 256;
        int brow = t >> 3, g = t & 7;
        int grow = rbase0 - 5 + brow;
        int tg0 = c0 - 8 + 8 * g;
        const float* px = xb + min(max(grow, 0), IMG - 1) * IMG;
        const float* py = yb + min(max(grow, 0), IMG - 1) * IMG;
        float4 fx[6], fy[6];
        issue_loads(px, py, tg0, fx, fy);
        conv_store(hb2, fx, fy, grow, tg0, brow, g);
    }
    // T14 prefetch of strip 1 rows (consumed after v-pass + carry)
    {
        int grow = rbase0 + 32 + 5 + hrow;
        const float* px = xb + min(max(grow, 0), IMG - 1) * IMG;
        const float* py = yb + min(max(grow, 0), IMG - 1) * IMG;
        issue_loads(px, py, gc0, pfx, pfy);
    }
    __syncthreads();
    lsum += vpass16(hb2, Gh, rb, cg);
    __syncthreads();

    for (int s = 1; s < NSTRIP; ++s) {
        // carry rows 32..41 -> 0..9 : 640 b64 moves (2 half2 each)
#pragma unroll
        for (int k = 0; k < 3; ++k) {
            int idx = tid + k * 256;
            if (idx < 640) {
                int q = idx / 160, rem2 = idx - q * 160;
                int rr = rem2 >> 4, p = rem2 & 15;
                *(float2*)&hb2[q][rr][2 * p] =
                    *(const float2*)&hb2[q][32 + rr][2 * p];
            }
        }
        __syncthreads();
        // h-conv from prefetched regs -> window rows 10..41
        {
            int grow = rbase0 + 32 * s + 5 + hrow;
            conv_store(hb2, pfx, pfy, grow, gc0, 10 + hrow, hg);
        }
        if (s < NSTRIP - 1) {
            int grow = rbase0 + 32 * (s + 1) + 5 + hrow;
            const float* px = xb + min(max(grow, 0), IMG - 1) * IMG;
            const float* py = yb + min(max(grow, 0), IMG - 1) * IMG;
            issue_loads(px, py, gc0, pfx, pfy);
        }
        __syncthreads();
        lsum += vpass16(hb2, Gh, rb, cg);
        __syncthreads();
    }

    // ---- block reduction -> plain store ----
#pragma unroll
    for (int off = 32; off > 0; off >>= 1)
        lsum += __shfl_down(lsum, off, 64);
    if ((tid & 63) == 0) wsum[tid >> 6] = lsum;
    __syncthreads();
    if (tid == 0)
        partial[bid] = wsum[0] + wsum[1] + wsum[2] + wsum[3];
}

__global__ __launch_bounds__(1024) void ssim_reduce_kernel(
    const float* __restrict__ partial, float* __restrict__ out)
{
    __shared__ double ws[16];
    const int tid = threadIdx.x;
    double s = 0.0;
#pragma unroll
    for (int i = 0; i < NBLK / 1024; ++i) s += (double)partial[tid + i * 1024];
#pragma unroll
    for (int off = 32; off > 0; off >>= 1)
        s += __shfl_down(s, off, 64);
    if ((tid & 63) == 0) ws[tid >> 6] = s;
    __syncthreads();
    if (tid == 0) {
        double t = 0.0;
#pragma unroll
        for (int w = 0; w < 16; ++w) t += ws[w];
        double mean = t / NPIX;
        out[0] = (float)(-log10(mean));  // loss
        out[1] = (float)mean;            // ssim_mean
    }
}

extern "C" void kernel_launch(void* const* d_in, const int* in_sizes, int n_in,
                              void* d_out, int out_size, void* d_ws, size_t ws_size,
                              hipStream_t stream)
{
    const float* x = (const float*)d_in[0];
    const float* y = (const float*)d_in[1];
    float* out     = (float*)d_out;
    float* partial = (float*)d_ws;      // 3072 floats, fully rewritten each call

    ssim_tile_kernel<<<NBLK, 256, 0, stream>>>(x, y, partial);
    ssim_reduce_kernel<<<1, 1024, 0, stream>>>(partial, out);
}